// Round 2
// baseline (263.782 us; speedup 1.0000x reference)
//
#include <hip/hip_runtime.h>

// P=1,048,576 params; E=8,388,608 edges; T=4,194,304 bytes; N=2,097,152 tokens.
//
// Measured HW facts driving this design:
//  - global atomicAdd caps at ~20.4 G/s regardless of locality (R1-R3) -> no
//    global atomics in hot paths; all accumulation in LDS.
//  - isolated small scattered stores cause ~3x write RMW amplification (R4) ->
//    scattered global writes staged via in-LDS counting sort, written as runs.
//  - NT loads on read-once input streams keep the fp table L2-resident (R10).
//  - R11 cache-policy split: intermediates (recs, rec2) written with normal
//    cached stores so L2 write-combines and they stay L3-resident.
//  - R12: records carry pidx (20b) instead of fx so phaseA is a pure
//    gather-free stream sort; fx computed in phaseC pass 1. phaseA persistent
//    2-chunk blocks with register prefetch. Result: phaseA 93 -> <88us, but
//    phaseC became the latency-bound hotspot (89us, VALUBusy 21%, VGPR=20:
//    compiler kept only ~2 loads in flight per thread).
//  - R13 (this round): MLP batching. phaseC pass 1 processes 8 records per
//    thread-iteration: 4x16B rec loads, then 8 INDEPENDENT fp gathers, then
//    16 fire-and-forget LDS atomics. Pass 2 same: 8 rec loads, 8 independent
//    acc[] LDS reads, then emit. All unrolled -> registers (~36-48 VGPR),
//    stays under the 64-VGPR tier so 2 blocks/CU occupancy is kept.
//
// rec64 = pos_low(13) | tok(21)<<13 | pidx(21)<<34 | bucket(9)<<55.
// acc u32 = cnt*2^26 + sum(fx), fx = round(fp[pidx] * 2^21)  (cnt<=~25).
// rec2 = tok_low(13) | wfx<<13,  wfx = round(w * 2^19) (19-bit signed).

typedef unsigned long long u64;
typedef unsigned int uint;
typedef int  vi4  __attribute__((ext_vector_type(4)));
typedef unsigned long long uv2 __attribute__((ext_vector_type(2)));

constexpr int NB   = 512;        // byte buckets  (bpos >> 13)
constexpr int PPB  = 8192;       // positions per byte bucket
constexpr int NB2  = 256;        // token buckets (tok >> 13)
constexpr int TOKB = 8192;       // tokens per token bucket
constexpr int CAP  = 17408;      // per-bucket capacity (mean 16384 + 8 sigma)
constexpr int CAP2 = 34816;      // per-token-bucket capacity (mean 32768 + 11s)

constexpr float V_SCALE = 2097152.0f;        // 2^21
constexpr float V_INV   = 1.0f / 2097152.0f;
constexpr float W_SCALE = 524288.0f;         // 2^19
constexpr float W_INV   = 1.0f / 524288.0f;

// Exclusive scan of 512 LDS entries by wave 0 only. lbase[512] = total.
__device__ __forceinline__ void wave_scan512(const uint* hist, uint* lbase,
                                             int t) {
    if (t < 64) {
        uint h[8];
        uint run = 0;
        #pragma unroll
        for (int j = 0; j < 8; ++j) { h[j] = run; run += hist[t * 8 + j]; }
        uint tot = run, inc = tot;
        #pragma unroll
        for (int d = 1; d < 64; d <<= 1) {
            uint up = __shfl_up(inc, d, 64);
            if (t >= d) inc += up;
        }
        uint excl = inc - tot;
        #pragma unroll
        for (int j = 0; j < 8; ++j) lbase[t * 8 + j] = excl + h[j];
        if (t == 63) lbase[512] = inc;
    }
}

// Exclusive scan of 256 LDS entries by wave 0 only. lbase[256] = total.
__device__ __forceinline__ void wave_scan256(const uint* hist, uint* lbase,
                                             int t) {
    if (t < 64) {
        uint h[4];
        uint run = 0;
        #pragma unroll
        for (int j = 0; j < 4; ++j) { h[j] = run; run += hist[t * 4 + j]; }
        uint tot = run, inc = tot;
        #pragma unroll
        for (int d = 1; d < 64; d <<= 1) {
            uint up = __shfl_up(inc, d, 64);
            if (t >= d) inc += up;
        }
        uint excl = inc - tot;
        #pragma unroll
        for (int j = 0; j < 4; ++j) lbase[t * 4 + j] = excl + h[j];
        if (t == 63) lbase[256] = inc;
    }
}

// ---------------- Phase A: bin edges into 512 byte-buckets ----------------
// Gather-free streaming sort; persistent blocks, 2 chunks each, prefetched.
constexpr int A_THREADS = 1024;
constexpr int A_EPT     = 8;
constexpr int A_CHUNK   = A_THREADS * A_EPT;   // 8192
constexpr int A_CPB     = 2;                   // chunks per block

__global__ __launch_bounds__(A_THREADS, 8) void phaseA(
    const int* __restrict__ pidx, const int* __restrict__ bpos,
    const int* __restrict__ tidx, u64* __restrict__ recs,
    uint* __restrict__ gcur, int E)
{
    __shared__ u64 stage[A_CHUNK];                 // 64 KB
    __shared__ uint hist[NB], lcur[NB], gbase[NB], lbase[NB + 1];  // ~8 KB
    int t = threadIdx.x;

    int c = blockIdx.x * A_CPB;
    int be0 = c * A_CHUNK + t * A_EPT;
    bool vec = (be0 + A_EPT) <= E;

    // initial NT loads of all three read-once streams for chunk 0
    vi4 b0, b1, p0, p1, k0, k1;
    if (vec) {
        b0 = __builtin_nontemporal_load((const vi4*)(bpos + be0));
        b1 = __builtin_nontemporal_load((const vi4*)(bpos + be0 + 4));
        p0 = __builtin_nontemporal_load((const vi4*)(pidx + be0));
        p1 = __builtin_nontemporal_load((const vi4*)(pidx + be0 + 4));
        k0 = __builtin_nontemporal_load((const vi4*)(tidx + be0));
        k1 = __builtin_nontemporal_load((const vi4*)(tidx + be0 + 4));
    }

    for (int cc = 0; cc < A_CPB; ++cc, ++c) {
        if (t < NB) { hist[t] = 0u; lcur[t] = 0u; }
        __syncthreads();

        int be = c * A_CHUNK + t * A_EPT;
        if (vec) {
            atomicAdd(&hist[((uint)b0.x) >> 13], 1u);
            atomicAdd(&hist[((uint)b0.y) >> 13], 1u);
            atomicAdd(&hist[((uint)b0.z) >> 13], 1u);
            atomicAdd(&hist[((uint)b0.w) >> 13], 1u);
            atomicAdd(&hist[((uint)b1.x) >> 13], 1u);
            atomicAdd(&hist[((uint)b1.y) >> 13], 1u);
            atomicAdd(&hist[((uint)b1.z) >> 13], 1u);
            atomicAdd(&hist[((uint)b1.w) >> 13], 1u);
        } else {
            for (int j = 0; j < A_EPT; ++j) {
                int e = be + j;
                if (e < E) atomicAdd(&hist[((uint)bpos[e]) >> 13], 1u);
            }
        }
        __syncthreads();

        // wave 0 scans; waves 8-15 issue the global cursor atomics concurrently.
        wave_scan512(hist, lbase, t);
        if (t >= 512) gbase[t - 512] = atomicAdd(&gcur[t - 512], hist[t - 512]);
        __syncthreads();

        // emit into LDS-staged counting sort (pure register/LDS, no value)
        auto emit = [&](int p, int tk, int pi) {
            uint b = ((uint)p) >> 13;
            u64 rec = (u64)(uint)(p & (PPB - 1))
                    | ((u64)(uint)tk << 13)
                    | ((u64)(uint)pi << 34)
                    | ((u64)b << 55);
            uint off = lbase[b] + atomicAdd(&lcur[b], 1u);
            stage[off] = rec;
        };
        if (vec) {
            emit(b0.x, k0.x, p0.x); emit(b0.y, k0.y, p0.y);
            emit(b0.z, k0.z, p0.z); emit(b0.w, k0.w, p0.w);
            emit(b1.x, k1.x, p1.x); emit(b1.y, k1.y, p1.y);
            emit(b1.z, k1.z, p1.z); emit(b1.w, k1.w, p1.w);
        } else {
            for (int j = 0; j < A_EPT; ++j) {
                int e = be + j;
                if (e < E) emit(bpos[e], tidx[e], pidx[e]);
            }
        }

        // prefetch next chunk's streams NOW (registers are dead after emit);
        // the ~900cy HBM latency drains under the barrier + writeout below.
        bool nvec = false;
        if (cc + 1 < A_CPB) {
            int nbe = (c + 1) * A_CHUNK + t * A_EPT;
            nvec = (nbe + A_EPT) <= E;
            if (nvec) {
                b0 = __builtin_nontemporal_load((const vi4*)(bpos + nbe));
                b1 = __builtin_nontemporal_load((const vi4*)(bpos + nbe + 4));
                p0 = __builtin_nontemporal_load((const vi4*)(pidx + nbe));
                p1 = __builtin_nontemporal_load((const vi4*)(pidx + nbe + 4));
                k0 = __builtin_nontemporal_load((const vi4*)(tidx + nbe));
                k1 = __builtin_nontemporal_load((const vi4*)(tidx + nbe + 4));
            }
        }
        __syncthreads();

        // write-out: bucket id from record bits; NORMAL cached stores
        // -> L2 write-combines runs, records stay L3-resident for phaseC.
        uint total = lbase[NB];
        for (uint i = t; i < total; i += A_THREADS) {
            u64 rc = stage[i];
            int b = (int)(rc >> 55);
            uint dst = gbase[b] + (i - lbase[b]);
            if (dst < (uint)CAP)
                recs[(size_t)b * CAP + dst] = rc;
        }
        vec = nvec;
        // no trailing barrier needed: next iteration's hist/lcur reset touches
        // disjoint LDS, and its own __syncthreads orders everything after.
    }
}

// ------- Phase C: per byte-bucket accumulate + emit token-bucket recs -------
constexpr int C_THREADS = 1024;
constexpr int C_CHUNK   = 8192;
constexpr int C_MAXCH   = (CAP + C_CHUNK - 1) / C_CHUNK;   // 3

__global__ __launch_bounds__(C_THREADS, 8) void phaseC(
    const float* __restrict__ fp,
    const u64* __restrict__ recs, const uint* __restrict__ gcur,
    uint* __restrict__ rec2, uint* __restrict__ gcur2)
{
    __shared__ uint acc[PPB];               // 32 KB
    __shared__ uint stage2[C_CHUNK];        // 32 KB
    __shared__ uint histc[C_MAXCH][NB2];    // 3 KB
    __shared__ uint lcur[NB2], gb[NB2], lbase[NB2 + 1];   // ~3 KB
    int t = threadIdx.x;
    int b = blockIdx.x;
    for (int i = t; i < PPB; i += C_THREADS) acc[i] = 0u;
    for (int i = t; i < C_MAXCH * NB2; i += C_THREADS) (&histc[0][0])[i] = 0u;
    if (t < NB2) lcur[t] = 0u;
    __syncthreads();

    uint n = min(gcur[b], (uint)CAP);
    const u64* r = recs + (size_t)b * CAP;

    // pass 1, batched x8: 4x16B NT rec loads -> 8 INDEPENDENT fp gathers
    // (cached, fp stays L2-resident) -> 16 fire-and-forget LDS atomics.
    // Groups of 8 are aligned so all 8 records share one histogram chunk.
    uint ng = n >> 3;
    for (uint g = t; g < ng; g += C_THREADS) {
        uint base = g * 8u;
        const uv2* pr = (const uv2*)(r + base);
        uv2 ra = __builtin_nontemporal_load(pr);
        uv2 rb = __builtin_nontemporal_load(pr + 1);
        uv2 rc2 = __builtin_nontemporal_load(pr + 2);
        uv2 rd = __builtin_nontemporal_load(pr + 3);
        u64 rr[8] = {ra.x, ra.y, rb.x, rb.y, rc2.x, rc2.y, rd.x, rd.y};
        uint ch = base / C_CHUNK;
        float v[8];
        #pragma unroll
        for (int j = 0; j < 8; ++j)
            v[j] = fp[(uint)(rr[j] >> 34) & 0x1FFFFFu];
        #pragma unroll
        for (int j = 0; j < 8; ++j) {
            int fx = (int)rintf(v[j] * V_SCALE);
            atomicAdd(&acc[(uint)rr[j] & (PPB - 1)], (uint)((1 << 26) + fx));
            atomicAdd(&histc[ch][(uint)(rr[j] >> 26) & 0xFFu], 1u);
        }
    }
    for (uint i = (ng << 3) + t; i < n; i += C_THREADS) {
        u64 rc = __builtin_nontemporal_load(r + i);
        uint pi = (uint)(rc >> 34) & 0x1FFFFFu;
        int fx = (int)rintf(fp[pi] * V_SCALE);
        atomicAdd(&acc[(uint)rc & (PPB - 1)], (uint)((1 << 26) + fx));
        atomicAdd(&histc[i / C_CHUNK][(uint)(rc >> 26) & 0xFFu], 1u);
    }
    __syncthreads();

    // ONE global-cursor atomic per bucket per block (wave 8), overlapped
    // with wave 0's chunk-0 scan below.
    if (t >= 512 && t < 512 + NB2) {
        int tb = t - 512;
        uint tot = histc[0][tb];
        #pragma unroll
        for (int c = 1; c < C_MAXCH; ++c) tot += histc[c][tb];
        gb[tb] = atomicAdd(&gcur2[tb], tot);
    }

    // pass 2, batched x8: chunked decode + LDS-staged emit + write-out
    uint ch = 0;
    for (uint c0 = 0; c0 < n; c0 += C_CHUNK, ++ch) {
        uint m = min((uint)C_CHUNK, n - c0);
        wave_scan256(histc[ch], lbase, t);
        __syncthreads();

        uint mg = m >> 3;
        for (uint g = t; g < mg; g += C_THREADS) {
            uint base = c0 + g * 8u;
            const uv2* pr = (const uv2*)(r + base);
            uv2 ra = __builtin_nontemporal_load(pr);
            uv2 rb = __builtin_nontemporal_load(pr + 1);
            uv2 rc2 = __builtin_nontemporal_load(pr + 2);
            uv2 rd = __builtin_nontemporal_load(pr + 3);
            u64 rr[8] = {ra.x, ra.y, rb.x, rb.y, rc2.x, rc2.y, rd.x, rd.y};
            uint av[8];
            #pragma unroll
            for (int j = 0; j < 8; ++j)
                av[j] = acc[(uint)rr[j] & (PPB - 1)];
            #pragma unroll
            for (int j = 0; j < 8; ++j) {
                uint tok = (uint)(rr[j] >> 13) & 0x1FFFFFu;
                uint c = (av[j] + (1u << 25)) >> 26;    // exact count >= 1
                int s = (int)(av[j] - (c << 26));       // signed sum * 2^21
                float w = (float)s * V_INV / (float)c;
                int wfx = (int)rintf(w * W_SCALE);
                uint tb = tok >> 13;
                uint off = lbase[tb] + atomicAdd(&lcur[tb], 1u);
                stage2[off] = (tok & (TOKB - 1)) | ((uint)wfx << 13);
            }
        }
        for (uint i = c0 + (mg << 3) + t; i < c0 + m; i += C_THREADS) {
            u64 rc = __builtin_nontemporal_load(r + i);
            uint pos = (uint)rc & (PPB - 1);
            uint tok = (uint)(rc >> 13) & 0x1FFFFFu;
            uint a = acc[pos];
            uint c = (a + (1u << 25)) >> 26;
            int s = (int)(a - (c << 26));
            float w = (float)s * V_INV / (float)c;
            int wfx = (int)rintf(w * W_SCALE);
            uint tb = tok >> 13;
            uint off = lbase[tb] + atomicAdd(&lcur[tb], 1u);
            stage2[off] = (tok & (TOKB - 1)) | ((uint)wfx << 13);
        }
        __syncthreads();
        // write-out: wave w copies buckets w, w+16, ... as contiguous runs
        // (normal cached stores -> rec2 stays L3-resident for phaseD)
        int w = t >> 6, lane = t & 63;
        for (int tb = w; tb < NB2; tb += 16) {
            uint base = lbase[tb];
            uint len  = lbase[tb + 1] - base;
            uint g    = gb[tb];
            for (uint j = lane; j < len; j += 64) {
                uint dst = g + j;
                if (dst < (uint)CAP2)
                    rec2[(size_t)tb * CAP2 + dst] = stage2[base + j];
            }
        }
        __syncthreads();
        if (t < NB2) { gb[t] += histc[ch][t]; lcur[t] = 0u; }
        __syncthreads();
    }
}

// ---------------- Phase D: per token-bucket reduce + output ----------------
constexpr int D_THREADS = 1024;

__global__ __launch_bounds__(D_THREADS) void phaseD(
    const uint* __restrict__ rec2, const uint* __restrict__ gcur2,
    float* __restrict__ out, int N)
{
    __shared__ int facc[TOKB];   // 32 KB
    int t = threadIdx.x;
    int b = blockIdx.x;
    for (int i = t; i < TOKB; i += D_THREADS) facc[i] = 0;
    __syncthreads();
    uint n = min(gcur2[b], (uint)CAP2);
    const uint* r = rec2 + (size_t)b * CAP2;
    uint n8 = n >> 3;
    for (uint i = t; i < n8; i += D_THREADS) {
        uint4 q0 = ((const uint4*)r)[2u * i];
        uint4 q1 = ((const uint4*)r)[2u * i + 1u];
        atomicAdd(&facc[q0.x & (TOKB - 1)], ((int)q0.x) >> 13);
        atomicAdd(&facc[q0.y & (TOKB - 1)], ((int)q0.y) >> 13);
        atomicAdd(&facc[q0.z & (TOKB - 1)], ((int)q0.z) >> 13);
        atomicAdd(&facc[q0.w & (TOKB - 1)], ((int)q0.w) >> 13);
        atomicAdd(&facc[q1.x & (TOKB - 1)], ((int)q1.x) >> 13);
        atomicAdd(&facc[q1.y & (TOKB - 1)], ((int)q1.y) >> 13);
        atomicAdd(&facc[q1.z & (TOKB - 1)], ((int)q1.z) >> 13);
        atomicAdd(&facc[q1.w & (TOKB - 1)], ((int)q1.w) >> 13);
    }
    for (uint i = (n8 << 3) + t; i < n; i += D_THREADS) {
        uint rc = r[i];
        atomicAdd(&facc[rc & (TOKB - 1)], ((int)rc) >> 13);
    }
    __syncthreads();
    int base = b * TOKB;
    for (int i = t; i < TOKB; i += D_THREADS) {
        int idx = base + i;
        if (idx < N)
            __builtin_nontemporal_store((float)facc[i] * W_INV, &out[idx]);
    }
}

// ---------------- fallback (R2 path) if workspace too small ----------------
__global__ void fb_scatter(const float* __restrict__ fp,
                           const int* __restrict__ pidx,
                           const int* __restrict__ bpos,
                           u64* __restrict__ bacc, int E) {
    int e = blockIdx.x * blockDim.x + threadIdx.x;
    if (e < E) {
        float v = fp[pidx[e]];
        long long fx = (long long)rintf(v * 4294967296.0f);
        atomicAdd(&bacc[bpos[e]], (1ULL << 39) + (u64)fx);
    }
}

__global__ void fb_tokens(const u64* __restrict__ bacc,
                          const int* __restrict__ bpos,
                          const int* __restrict__ tidx,
                          float* __restrict__ out, int E) {
    int e = blockIdx.x * blockDim.x + threadIdx.x;
    if (e < E) {
        u64 v = bacc[bpos[e]];
        long long cnt = (long long)((v + (1ULL << 38)) >> 39);
        long long s   = (long long)(v - ((u64)cnt << 39));
        atomicAdd(&out[tidx[e]], (float)s * (1.0f / 4294967296.0f) / (float)cnt);
    }
}

extern "C" void kernel_launch(void* const* d_in, const int* in_sizes, int n_in,
                              void* d_out, int out_size, void* d_ws, size_t ws_size,
                              hipStream_t stream) {
    const float* flat_params   = (const float*)d_in[0];
    const int*   occ_param_idx = (const int*)d_in[1];
    const int*   occ_byte_pos  = (const int*)d_in[2];
    const int*   occ_token_idx = (const int*)d_in[3];

    const int P = in_sizes[0];            // 1,048,576
    const int E = in_sizes[1];            // 8,388,608
    const int N = out_size;               // 2,097,152

    const size_t REC_BYTES  = (size_t)NB  * CAP  * 8;   // 71.3 MB
    const size_t REC2_BYTES = (size_t)NB2 * CAP2 * 4;   // 35.7 MB
    const size_t NEED = 4096 + REC_BYTES + REC2_BYTES;  // ~107 MB

    if (ws_size >= NEED && N <= NB2 * TOKB && P <= (1 << 21)) {
        uint* gcur  = (uint*)d_ws;                  // 2 KB
        uint* gcur2 = (uint*)((char*)d_ws + 2048);  // 1 KB
        u64* recs = (u64*)((char*)d_ws + 4096);
        uint* rec2 = (uint*)((char*)d_ws + 4096 + REC_BYTES);

        (void)hipMemsetAsync(d_ws, 0, 4096, stream);   // both cursor arrays

        int nchunks = (E + A_CHUNK - 1) / A_CHUNK;          // 1024
        int gridA = (nchunks + A_CPB - 1) / A_CPB;          // 512
        phaseA<<<gridA, A_THREADS, 0, stream>>>(occ_param_idx, occ_byte_pos,
                                                occ_token_idx, recs, gcur, E);
        phaseC<<<NB, C_THREADS, 0, stream>>>(flat_params, recs, gcur,
                                             rec2, gcur2);
        phaseD<<<NB2, D_THREADS, 0, stream>>>(rec2, gcur2, (float*)d_out, N);
    } else {
        u64* bacc = (u64*)d_ws;
        (void)hipMemsetAsync(bacc, 0, (size_t)4194304 * 8, stream);
        (void)hipMemsetAsync(d_out, 0, (size_t)N * sizeof(float), stream);
        int gridE = (E + 255) / 256;
        fb_scatter<<<gridE, 256, 0, stream>>>(flat_params, occ_param_idx,
                                              occ_byte_pos, bacc, E);
        fb_tokens<<<gridE, 256, 0, stream>>>(bacc, occ_byte_pos,
                                             occ_token_idx, (float*)d_out, E);
    }
}

// Round 4
// 254.567 us; speedup vs baseline: 1.0362x; 1.0362x over previous
//
#include <hip/hip_runtime.h>

// P=1,048,576 params; E=8,388,608 edges; T=4,194,304 bytes; N=2,097,152 tokens.
//
// Measured HW facts driving this design:
//  - global atomicAdd caps at ~20.4 G/s regardless of locality (R1-R3) -> no
//    global atomics in hot paths; all accumulation in LDS.
//  - isolated small scattered stores cause ~3x write RMW amplification (R4) ->
//    scattered global writes staged via in-LDS counting sort, written as runs.
//  - NT loads on read-once input streams keep the fp table L2-resident (R10).
//  - R11 cache-policy split: intermediates (recs, rec2) written with normal
//    cached stores so L2 write-combines and they stay L3-resident.
//  - R12: records carry pidx instead of fx -> phaseA gather-free; gather in
//    phaseC pass 1. phaseA 93 -> ~85us; phaseC 89us (latency-bound, VGPR=20).
//  - R13 REGRESSION (reverted): batching with per-thread-contiguous 64B
//    blocks broke NT coalescing (lanes at stride 64B -> 4x line refetch,
//    FETCH +34MB, dur 89->104). Lesson: MLP batching must keep wave-coalesced
//    stride (i + k*C_THREADS); NT loads make per-thread blocks fatal.
//  - R14: (a) strip-mined MLP with COALESCED stride: pass 1 issues 4
//    independent 16B rec loads (1KB/wave each) then 8 independent fp gathers
//    then 16 fire-and-forget LDS atomics; pass 2 strip-mined x2.
//    (b) phaseD was 1 block/CU (16 waves, half occupancy): NB2 512, TOKB
//    4096 -> facc 16KB, 2 blocks/CU, 32 waves. rec2 = tok_low(12)|wfx<<12.
//  - R15 (this round): R14 bench never ran (container acquire failed twice;
//    no compile/correctness signal). Source re-audited for hangs (barrier
//    uniformity, LDS fit, chunk accounting, alignment) - clean. Resubmitting
//    identical kernel to get the measurement.
//
// rec64 = pos_low(13) | tok(21)<<13 | pidx(21)<<34 | bucket(9)<<55.
// acc u32 = cnt*2^26 + sum(fx), fx = round(fp[pidx] * 2^21)  (cnt<=~25).
// rec2 = tok_low(12) | wfx<<12,  wfx = round(w * 2^19) (fits 20-bit signed).

typedef unsigned long long u64;
typedef unsigned int uint;
typedef int  vi4  __attribute__((ext_vector_type(4)));
typedef unsigned long long uv2 __attribute__((ext_vector_type(2)));

constexpr int NB   = 512;        // byte buckets  (bpos >> 13)
constexpr int PPB  = 8192;       // positions per byte bucket
constexpr int NB2  = 512;        // token buckets (tok >> 12)
constexpr int TOKB = 4096;       // tokens per token bucket
constexpr int CAP  = 17408;      // per-bucket capacity (mean 16384 + 8 sigma)
constexpr int CAP2 = 17408;      // per-token-bucket capacity (mean 16384 + 8s)

constexpr float V_SCALE = 2097152.0f;        // 2^21
constexpr float V_INV   = 1.0f / 2097152.0f;
constexpr float W_SCALE = 524288.0f;         // 2^19
constexpr float W_INV   = 1.0f / 524288.0f;

// Exclusive scan of 512 LDS entries by wave 0 only. lbase[512] = total.
__device__ __forceinline__ void wave_scan512(const uint* hist, uint* lbase,
                                             int t) {
    if (t < 64) {
        uint h[8];
        uint run = 0;
        #pragma unroll
        for (int j = 0; j < 8; ++j) { h[j] = run; run += hist[t * 8 + j]; }
        uint tot = run, inc = tot;
        #pragma unroll
        for (int d = 1; d < 64; d <<= 1) {
            uint up = __shfl_up(inc, d, 64);
            if (t >= d) inc += up;
        }
        uint excl = inc - tot;
        #pragma unroll
        for (int j = 0; j < 8; ++j) lbase[t * 8 + j] = excl + h[j];
        if (t == 63) lbase[512] = inc;
    }
}

// ---------------- Phase A: bin edges into 512 byte-buckets ----------------
// Gather-free streaming sort; persistent blocks, 2 chunks each, prefetched.
constexpr int A_THREADS = 1024;
constexpr int A_EPT     = 8;
constexpr int A_CHUNK   = A_THREADS * A_EPT;   // 8192
constexpr int A_CPB     = 2;                   // chunks per block

__global__ __launch_bounds__(A_THREADS, 8) void phaseA(
    const int* __restrict__ pidx, const int* __restrict__ bpos,
    const int* __restrict__ tidx, u64* __restrict__ recs,
    uint* __restrict__ gcur, int E)
{
    __shared__ u64 stage[A_CHUNK];                 // 64 KB
    __shared__ uint hist[NB], lcur[NB], gbase[NB], lbase[NB + 1];  // ~8 KB
    int t = threadIdx.x;

    int c = blockIdx.x * A_CPB;
    int be0 = c * A_CHUNK + t * A_EPT;
    bool vec = (be0 + A_EPT) <= E;

    // initial NT loads of all three read-once streams for chunk 0
    vi4 b0, b1, p0, p1, k0, k1;
    if (vec) {
        b0 = __builtin_nontemporal_load((const vi4*)(bpos + be0));
        b1 = __builtin_nontemporal_load((const vi4*)(bpos + be0 + 4));
        p0 = __builtin_nontemporal_load((const vi4*)(pidx + be0));
        p1 = __builtin_nontemporal_load((const vi4*)(pidx + be0 + 4));
        k0 = __builtin_nontemporal_load((const vi4*)(tidx + be0));
        k1 = __builtin_nontemporal_load((const vi4*)(tidx + be0 + 4));
    }

    for (int cc = 0; cc < A_CPB; ++cc, ++c) {
        if (t < NB) { hist[t] = 0u; lcur[t] = 0u; }
        __syncthreads();

        int be = c * A_CHUNK + t * A_EPT;
        if (vec) {
            atomicAdd(&hist[((uint)b0.x) >> 13], 1u);
            atomicAdd(&hist[((uint)b0.y) >> 13], 1u);
            atomicAdd(&hist[((uint)b0.z) >> 13], 1u);
            atomicAdd(&hist[((uint)b0.w) >> 13], 1u);
            atomicAdd(&hist[((uint)b1.x) >> 13], 1u);
            atomicAdd(&hist[((uint)b1.y) >> 13], 1u);
            atomicAdd(&hist[((uint)b1.z) >> 13], 1u);
            atomicAdd(&hist[((uint)b1.w) >> 13], 1u);
        } else {
            for (int j = 0; j < A_EPT; ++j) {
                int e = be + j;
                if (e < E) atomicAdd(&hist[((uint)bpos[e]) >> 13], 1u);
            }
        }
        __syncthreads();

        // wave 0 scans; waves 8-15 issue the global cursor atomics concurrently.
        wave_scan512(hist, lbase, t);
        if (t >= 512) gbase[t - 512] = atomicAdd(&gcur[t - 512], hist[t - 512]);
        __syncthreads();

        // emit into LDS-staged counting sort (pure register/LDS, no value)
        auto emit = [&](int p, int tk, int pi) {
            uint b = ((uint)p) >> 13;
            u64 rec = (u64)(uint)(p & (PPB - 1))
                    | ((u64)(uint)tk << 13)
                    | ((u64)(uint)pi << 34)
                    | ((u64)b << 55);
            uint off = lbase[b] + atomicAdd(&lcur[b], 1u);
            stage[off] = rec;
        };
        if (vec) {
            emit(b0.x, k0.x, p0.x); emit(b0.y, k0.y, p0.y);
            emit(b0.z, k0.z, p0.z); emit(b0.w, k0.w, p0.w);
            emit(b1.x, k1.x, p1.x); emit(b1.y, k1.y, p1.y);
            emit(b1.z, k1.z, p1.z); emit(b1.w, k1.w, p1.w);
        } else {
            for (int j = 0; j < A_EPT; ++j) {
                int e = be + j;
                if (e < E) emit(bpos[e], tidx[e], pidx[e]);
            }
        }

        // prefetch next chunk's streams NOW (registers are dead after emit);
        // the ~900cy HBM latency drains under the barrier + writeout below.
        bool nvec = false;
        if (cc + 1 < A_CPB) {
            int nbe = (c + 1) * A_CHUNK + t * A_EPT;
            nvec = (nbe + A_EPT) <= E;
            if (nvec) {
                b0 = __builtin_nontemporal_load((const vi4*)(bpos + nbe));
                b1 = __builtin_nontemporal_load((const vi4*)(bpos + nbe + 4));
                p0 = __builtin_nontemporal_load((const vi4*)(pidx + nbe));
                p1 = __builtin_nontemporal_load((const vi4*)(pidx + nbe + 4));
                k0 = __builtin_nontemporal_load((const vi4*)(tidx + nbe));
                k1 = __builtin_nontemporal_load((const vi4*)(tidx + nbe + 4));
            }
        }
        __syncthreads();

        // write-out: bucket id from record bits; NORMAL cached stores
        // -> L2 write-combines runs, records stay L3-resident for phaseC.
        uint total = lbase[NB];
        for (uint i = t; i < total; i += A_THREADS) {
            u64 rc = stage[i];
            int b = (int)(rc >> 55);
            uint dst = gbase[b] + (i - lbase[b]);
            if (dst < (uint)CAP)
                recs[(size_t)b * CAP + dst] = rc;
        }
        vec = nvec;
    }
}

// ------- Phase C: per byte-bucket accumulate + emit token-bucket recs -------
constexpr int C_THREADS = 1024;
constexpr int C_CHUNK   = 8192;
constexpr int C_MAXCH   = (CAP + C_CHUNK - 1) / C_CHUNK;   // 3

__global__ __launch_bounds__(C_THREADS, 8) void phaseC(
    const float* __restrict__ fp,
    const u64* __restrict__ recs, const uint* __restrict__ gcur,
    uint* __restrict__ rec2, uint* __restrict__ gcur2)
{
    __shared__ uint acc[PPB];               // 32 KB
    __shared__ uint stage2[C_CHUNK];        // 32 KB
    __shared__ uint histc[C_MAXCH][NB2];    // 6 KB
    __shared__ uint lcur[NB2], gb[NB2], lbase[NB2 + 1];   // ~6 KB
    int t = threadIdx.x;
    int b = blockIdx.x;
    for (int i = t; i < PPB; i += C_THREADS) acc[i] = 0u;
    for (int i = t; i < C_MAXCH * NB2; i += C_THREADS) (&histc[0][0])[i] = 0u;
    if (t < NB2) lcur[t] = 0u;
    __syncthreads();

    uint n = min(gcur[b], (uint)CAP);
    const u64* r = recs + (size_t)b * CAP;

    // pass 1: strip-mined x4 with COALESCED stride (each NT load = 1KB/wave).
    // 4 independent rec loads -> 8 independent fp gathers -> 16 LDS atomics.
    auto upd = [&](u64 rc, float v, uint ch) {
        int fx = (int)rintf(v * V_SCALE);
        atomicAdd(&acc[(uint)rc & (PPB - 1)], (uint)((1 << 26) + fx));
        atomicAdd(&histc[ch][(uint)(rc >> 25) & 0x1FFu], 1u);  // tok>>12
    };
    uint np = n >> 1;                        // uv2 pairs
    const uv2* pr = (const uv2*)r;
    uint i = t;
    for (; i + 3u * C_THREADS < np; i += 4u * C_THREADS) {
        uv2 x0 = __builtin_nontemporal_load(pr + i);
        uv2 x1 = __builtin_nontemporal_load(pr + i + C_THREADS);
        uv2 x2 = __builtin_nontemporal_load(pr + i + 2u * C_THREADS);
        uv2 x3 = __builtin_nontemporal_load(pr + i + 3u * C_THREADS);
        float v0 = fp[(uint)(x0.x >> 34) & 0x1FFFFFu];
        float v1 = fp[(uint)(x0.y >> 34) & 0x1FFFFFu];
        float v2 = fp[(uint)(x1.x >> 34) & 0x1FFFFFu];
        float v3 = fp[(uint)(x1.y >> 34) & 0x1FFFFFu];
        float v4 = fp[(uint)(x2.x >> 34) & 0x1FFFFFu];
        float v5 = fp[(uint)(x2.y >> 34) & 0x1FFFFFu];
        float v6 = fp[(uint)(x3.x >> 34) & 0x1FFFFFu];
        float v7 = fp[(uint)(x3.y >> 34) & 0x1FFFFFu];
        uint c0 = i >> 12;                         // pair>>12 == elem>>13
        uint c1 = (i + C_THREADS) >> 12;
        uint c2 = (i + 2u * C_THREADS) >> 12;
        uint c3 = (i + 3u * C_THREADS) >> 12;
        upd(x0.x, v0, c0); upd(x0.y, v1, c0);
        upd(x1.x, v2, c1); upd(x1.y, v3, c1);
        upd(x2.x, v4, c2); upd(x2.y, v5, c2);
        upd(x3.x, v6, c3); upd(x3.y, v7, c3);
    }
    for (; i < np; i += C_THREADS) {
        uv2 x = __builtin_nontemporal_load(pr + i);
        uint ch = i >> 12;
        float va = fp[(uint)(x.x >> 34) & 0x1FFFFFu];
        float vb = fp[(uint)(x.y >> 34) & 0x1FFFFFu];
        upd(x.x, va, ch); upd(x.y, vb, ch);
    }
    if ((n & 1u) && t == 0) {
        u64 rc = __builtin_nontemporal_load(r + n - 1);
        upd(rc, fp[(uint)(rc >> 34) & 0x1FFFFFu], (n - 1) / C_CHUNK);
    }
    __syncthreads();

    // ONE global-cursor atomic per bucket per block (waves 8-15), overlapped
    // with wave 0's chunk-0 scan below.
    if (t >= 512) {
        int tb = t - 512;
        uint tot = histc[0][tb];
        #pragma unroll
        for (int c = 1; c < C_MAXCH; ++c) tot += histc[c][tb];
        gb[tb] = atomicAdd(&gcur2[tb], tot);
    }

    // pass 2: strip-mined x2 chunked decode + LDS-staged emit + write-out
    auto emit = [&](u64 rc, uint a) {
        uint tok = (uint)(rc >> 13) & 0x1FFFFFu;
        uint c = (a + (1u << 25)) >> 26;        // exact count >= 1
        int s = (int)(a - (c << 26));           // signed sum * 2^21
        float w = (float)s * V_INV / (float)c;
        int wfx = (int)rintf(w * W_SCALE);
        uint tb = tok >> 12;
        uint off = lbase[tb] + atomicAdd(&lcur[tb], 1u);
        stage2[off] = (tok & (TOKB - 1)) | ((uint)wfx << 12);
    };
    uint ch = 0;
    for (uint c0 = 0; c0 < n; c0 += C_CHUNK, ++ch) {
        uint m = min((uint)C_CHUNK, n - c0);
        wave_scan512(histc[ch], lbase, t);
        __syncthreads();

        uint mp = m >> 1;
        const uv2* pc = (const uv2*)(r + c0);
        uint j = t;
        for (; j + C_THREADS < mp; j += 2u * C_THREADS) {
            uv2 x0 = __builtin_nontemporal_load(pc + j);
            uv2 x1 = __builtin_nontemporal_load(pc + j + C_THREADS);
            uint a0 = acc[(uint)x0.x & (PPB - 1)];
            uint a1 = acc[(uint)x0.y & (PPB - 1)];
            uint a2 = acc[(uint)x1.x & (PPB - 1)];
            uint a3 = acc[(uint)x1.y & (PPB - 1)];
            emit(x0.x, a0); emit(x0.y, a1);
            emit(x1.x, a2); emit(x1.y, a3);
        }
        for (; j < mp; j += C_THREADS) {
            uv2 x = __builtin_nontemporal_load(pc + j);
            uint a0 = acc[(uint)x.x & (PPB - 1)];
            uint a1 = acc[(uint)x.y & (PPB - 1)];
            emit(x.x, a0); emit(x.y, a1);
        }
        if ((m & 1u) && t == 0) {
            u64 rc = __builtin_nontemporal_load(r + c0 + m - 1);
            emit(rc, acc[(uint)rc & (PPB - 1)]);
        }
        __syncthreads();
        // write-out: wave w copies buckets w, w+16, ... as contiguous runs
        // (normal cached stores -> rec2 stays L3-resident for phaseD)
        int w = t >> 6, lane = t & 63;
        for (int tb = w; tb < NB2; tb += 16) {
            uint base = lbase[tb];
            uint len  = lbase[tb + 1] - base;
            uint g    = gb[tb];
            for (uint q = lane; q < len; q += 64) {
                uint dst = g + q;
                if (dst < (uint)CAP2)
                    rec2[(size_t)tb * CAP2 + dst] = stage2[base + q];
            }
        }
        __syncthreads();
        if (t < NB2) { gb[t] += histc[ch][t]; lcur[t] = 0u; }
        __syncthreads();
    }
}

// ---------------- Phase D: per token-bucket reduce + output ----------------
constexpr int D_THREADS = 1024;

__global__ __launch_bounds__(D_THREADS) void phaseD(
    const uint* __restrict__ rec2, const uint* __restrict__ gcur2,
    float* __restrict__ out, int N)
{
    __shared__ int facc[TOKB];   // 16 KB -> 2 blocks/CU, 32 waves
    int t = threadIdx.x;
    int b = blockIdx.x;
    for (int i = t; i < TOKB; i += D_THREADS) facc[i] = 0;
    __syncthreads();
    uint n = min(gcur2[b], (uint)CAP2);
    const uint* r = rec2 + (size_t)b * CAP2;
    uint n4 = n >> 2;
    uint i = t;
    for (; i + D_THREADS < n4; i += 2u * D_THREADS) {
        uint4 q0 = ((const uint4*)r)[i];
        uint4 q1 = ((const uint4*)r)[i + D_THREADS];
        atomicAdd(&facc[q0.x & (TOKB - 1)], ((int)q0.x) >> 12);
        atomicAdd(&facc[q0.y & (TOKB - 1)], ((int)q0.y) >> 12);
        atomicAdd(&facc[q0.z & (TOKB - 1)], ((int)q0.z) >> 12);
        atomicAdd(&facc[q0.w & (TOKB - 1)], ((int)q0.w) >> 12);
        atomicAdd(&facc[q1.x & (TOKB - 1)], ((int)q1.x) >> 12);
        atomicAdd(&facc[q1.y & (TOKB - 1)], ((int)q1.y) >> 12);
        atomicAdd(&facc[q1.z & (TOKB - 1)], ((int)q1.z) >> 12);
        atomicAdd(&facc[q1.w & (TOKB - 1)], ((int)q1.w) >> 12);
    }
    for (; i < n4; i += D_THREADS) {
        uint4 q = ((const uint4*)r)[i];
        atomicAdd(&facc[q.x & (TOKB - 1)], ((int)q.x) >> 12);
        atomicAdd(&facc[q.y & (TOKB - 1)], ((int)q.y) >> 12);
        atomicAdd(&facc[q.z & (TOKB - 1)], ((int)q.z) >> 12);
        atomicAdd(&facc[q.w & (TOKB - 1)], ((int)q.w) >> 12);
    }
    for (uint k = (n4 << 2) + t; k < n; k += D_THREADS) {
        uint rc = r[k];
        atomicAdd(&facc[rc & (TOKB - 1)], ((int)rc) >> 12);
    }
    __syncthreads();
    int base = b * TOKB;
    for (int i2 = t; i2 < TOKB; i2 += D_THREADS) {
        int idx = base + i2;
        if (idx < N)
            __builtin_nontemporal_store((float)facc[i2] * W_INV, &out[idx]);
    }
}

// ---------------- fallback (R2 path) if workspace too small ----------------
__global__ void fb_scatter(const float* __restrict__ fp,
                           const int* __restrict__ pidx,
                           const int* __restrict__ bpos,
                           u64* __restrict__ bacc, int E) {
    int e = blockIdx.x * blockDim.x + threadIdx.x;
    if (e < E) {
        float v = fp[pidx[e]];
        long long fx = (long long)rintf(v * 4294967296.0f);
        atomicAdd(&bacc[bpos[e]], (1ULL << 39) + (u64)fx);
    }
}

__global__ void fb_tokens(const u64* __restrict__ bacc,
                          const int* __restrict__ bpos,
                          const int* __restrict__ tidx,
                          float* __restrict__ out, int E) {
    int e = blockIdx.x * blockDim.x + threadIdx.x;
    if (e < E) {
        u64 v = bacc[bpos[e]];
        long long cnt = (long long)((v + (1ULL << 38)) >> 39);
        long long s   = (long long)(v - ((u64)cnt << 39));
        atomicAdd(&out[tidx[e]], (float)s * (1.0f / 4294967296.0f) / (float)cnt);
    }
}

extern "C" void kernel_launch(void* const* d_in, const int* in_sizes, int n_in,
                              void* d_out, int out_size, void* d_ws, size_t ws_size,
                              hipStream_t stream) {
    const float* flat_params   = (const float*)d_in[0];
    const int*   occ_param_idx = (const int*)d_in[1];
    const int*   occ_byte_pos  = (const int*)d_in[2];
    const int*   occ_token_idx = (const int*)d_in[3];

    const int P = in_sizes[0];            // 1,048,576
    const int E = in_sizes[1];            // 8,388,608
    const int N = out_size;               // 2,097,152

    const size_t REC_BYTES  = (size_t)NB  * CAP  * 8;   // 71.3 MB
    const size_t REC2_BYTES = (size_t)NB2 * CAP2 * 4;   // 35.7 MB
    const size_t NEED = 4096 + REC_BYTES + REC2_BYTES;  // ~107 MB

    if (ws_size >= NEED && N <= NB2 * TOKB && P <= (1 << 21)) {
        uint* gcur  = (uint*)d_ws;                  // 2 KB (512 u32)
        uint* gcur2 = (uint*)((char*)d_ws + 2048);  // 2 KB (512 u32)
        u64* recs = (u64*)((char*)d_ws + 4096);
        uint* rec2 = (uint*)((char*)d_ws + 4096 + REC_BYTES);

        (void)hipMemsetAsync(d_ws, 0, 4096, stream);   // both cursor arrays

        int nchunks = (E + A_CHUNK - 1) / A_CHUNK;          // 1024
        int gridA = (nchunks + A_CPB - 1) / A_CPB;          // 512
        phaseA<<<gridA, A_THREADS, 0, stream>>>(occ_param_idx, occ_byte_pos,
                                                occ_token_idx, recs, gcur, E);
        phaseC<<<NB, C_THREADS, 0, stream>>>(flat_params, recs, gcur,
                                             rec2, gcur2);
        phaseD<<<NB2, D_THREADS, 0, stream>>>(rec2, gcur2, (float*)d_out, N);
    } else {
        u64* bacc = (u64*)d_ws;
        (void)hipMemsetAsync(bacc, 0, (size_t)4194304 * 8, stream);
        (void)hipMemsetAsync(d_out, 0, (size_t)N * sizeof(float), stream);
        int gridE = (E + 255) / 256;
        fb_scatter<<<gridE, 256, 0, stream>>>(flat_params, occ_param_idx,
                                              occ_byte_pos, bacc, E);
        fb_tokens<<<gridE, 256, 0, stream>>>(bacc, occ_byte_pos,
                                             occ_token_idx, (float*)d_out, E);
    }
}

// Round 5
// 244.275 us; speedup vs baseline: 1.0799x; 1.0421x over previous
//
#include <hip/hip_runtime.h>

// P=1,048,576 params; E=8,388,608 edges; T=4,194,304 bytes; N=2,097,152 tokens.
//
// Measured HW facts driving this design:
//  - global atomicAdd caps at ~20.4 G/s regardless of locality (R1-R3) -> no
//    global atomics in hot paths; all accumulation in LDS.
//  - isolated small scattered stores cause ~3x write RMW amplification (R4) ->
//    scattered global writes staged via in-LDS counting sort, written as runs
//    of >=128B (R15: 64B runs re-trigger RMW: WRITE +6.5MB, FETCH +10MB).
//  - NT loads on read-once input streams keep the fp table L2-resident (R10).
//  - R11 cache-policy split: intermediates (recs, rec2) written with normal
//    cached stores so L2 write-combines and they stay L3-resident.
//  - R12: records carry pidx instead of fx -> phaseA gather-free; gather in
//    phaseC pass 1. phaseA 93 -> ~85us; phaseC 89us (latency-bound, VGPR=20).
//  - R13 REGRESSION (reverted): per-thread-contiguous NT batching broke
//    coalescing. Lesson: MLP batching must keep wave-coalesced stride.
//  - R15: strip-mined MLP (coalesced) confirmed: VALUBusy 21->28.6, VGPR 32.
//    But NB2=512 shrank rec2 runs to 64B -> RMW amplification; phaseC flat,
//    total +6. ALSO: phaseD 2 blocks/CU did NOT improve total -> phaseD's
//    ~65us is NOT occupancy-bound (cause still unknown; counters hidden).
//  - R16 (this round): revert NB2=256/TOKB=8192 (128B runs) keeping the
//    strip-mine; fold pass-2 gb/lcur update into write-out (bucket tb owned
//    by wave tb%16 every chunk -> race-free, 4->3 barriers/chunk); phaseD
//    4-deep load batching to probe whether D responds to MLP.
//
// rec64 = pos_low(13) | tok(21)<<13 | pidx(21)<<34 | bucket(9)<<55.
// acc u32 = cnt*2^26 + sum(fx), fx = round(fp[pidx] * 2^21)  (cnt<=~25).
// rec2 = tok_low(13) | wfx<<13,  wfx = round(w * 2^19) (19-bit signed).

typedef unsigned long long u64;
typedef unsigned int uint;
typedef int  vi4  __attribute__((ext_vector_type(4)));
typedef unsigned long long uv2 __attribute__((ext_vector_type(2)));

constexpr int NB   = 512;        // byte buckets  (bpos >> 13)
constexpr int PPB  = 8192;       // positions per byte bucket
constexpr int NB2  = 256;        // token buckets (tok >> 13)
constexpr int TOKB = 8192;       // tokens per token bucket
constexpr int CAP  = 17408;      // per-bucket capacity (mean 16384 + 8 sigma)
constexpr int CAP2 = 34816;      // per-token-bucket capacity (mean 32768 + 11s)

constexpr float V_SCALE = 2097152.0f;        // 2^21
constexpr float V_INV   = 1.0f / 2097152.0f;
constexpr float W_SCALE = 524288.0f;         // 2^19
constexpr float W_INV   = 1.0f / 524288.0f;

// Exclusive scan of 512 LDS entries by wave 0 only. lbase[512] = total.
__device__ __forceinline__ void wave_scan512(const uint* hist, uint* lbase,
                                             int t) {
    if (t < 64) {
        uint h[8];
        uint run = 0;
        #pragma unroll
        for (int j = 0; j < 8; ++j) { h[j] = run; run += hist[t * 8 + j]; }
        uint tot = run, inc = tot;
        #pragma unroll
        for (int d = 1; d < 64; d <<= 1) {
            uint up = __shfl_up(inc, d, 64);
            if (t >= d) inc += up;
        }
        uint excl = inc - tot;
        #pragma unroll
        for (int j = 0; j < 8; ++j) lbase[t * 8 + j] = excl + h[j];
        if (t == 63) lbase[512] = inc;
    }
}

// Exclusive scan of 256 LDS entries by wave 0 only. lbase[256] = total.
__device__ __forceinline__ void wave_scan256(const uint* hist, uint* lbase,
                                             int t) {
    if (t < 64) {
        uint h[4];
        uint run = 0;
        #pragma unroll
        for (int j = 0; j < 4; ++j) { h[j] = run; run += hist[t * 4 + j]; }
        uint tot = run, inc = tot;
        #pragma unroll
        for (int d = 1; d < 64; d <<= 1) {
            uint up = __shfl_up(inc, d, 64);
            if (t >= d) inc += up;
        }
        uint excl = inc - tot;
        #pragma unroll
        for (int j = 0; j < 4; ++j) lbase[t * 4 + j] = excl + h[j];
        if (t == 63) lbase[256] = inc;
    }
}

// ---------------- Phase A: bin edges into 512 byte-buckets ----------------
// Gather-free streaming sort; persistent blocks, 2 chunks each, prefetched.
constexpr int A_THREADS = 1024;
constexpr int A_EPT     = 8;
constexpr int A_CHUNK   = A_THREADS * A_EPT;   // 8192
constexpr int A_CPB     = 2;                   // chunks per block

__global__ __launch_bounds__(A_THREADS, 8) void phaseA(
    const int* __restrict__ pidx, const int* __restrict__ bpos,
    const int* __restrict__ tidx, u64* __restrict__ recs,
    uint* __restrict__ gcur, int E)
{
    __shared__ u64 stage[A_CHUNK];                 // 64 KB
    __shared__ uint hist[NB], lcur[NB], gbase[NB], lbase[NB + 1];  // ~8 KB
    int t = threadIdx.x;

    int c = blockIdx.x * A_CPB;
    int be0 = c * A_CHUNK + t * A_EPT;
    bool vec = (be0 + A_EPT) <= E;

    // initial NT loads of all three read-once streams for chunk 0
    vi4 b0, b1, p0, p1, k0, k1;
    if (vec) {
        b0 = __builtin_nontemporal_load((const vi4*)(bpos + be0));
        b1 = __builtin_nontemporal_load((const vi4*)(bpos + be0 + 4));
        p0 = __builtin_nontemporal_load((const vi4*)(pidx + be0));
        p1 = __builtin_nontemporal_load((const vi4*)(pidx + be0 + 4));
        k0 = __builtin_nontemporal_load((const vi4*)(tidx + be0));
        k1 = __builtin_nontemporal_load((const vi4*)(tidx + be0 + 4));
    }

    for (int cc = 0; cc < A_CPB; ++cc, ++c) {
        if (t < NB) { hist[t] = 0u; lcur[t] = 0u; }
        __syncthreads();

        int be = c * A_CHUNK + t * A_EPT;
        if (vec) {
            atomicAdd(&hist[((uint)b0.x) >> 13], 1u);
            atomicAdd(&hist[((uint)b0.y) >> 13], 1u);
            atomicAdd(&hist[((uint)b0.z) >> 13], 1u);
            atomicAdd(&hist[((uint)b0.w) >> 13], 1u);
            atomicAdd(&hist[((uint)b1.x) >> 13], 1u);
            atomicAdd(&hist[((uint)b1.y) >> 13], 1u);
            atomicAdd(&hist[((uint)b1.z) >> 13], 1u);
            atomicAdd(&hist[((uint)b1.w) >> 13], 1u);
        } else {
            for (int j = 0; j < A_EPT; ++j) {
                int e = be + j;
                if (e < E) atomicAdd(&hist[((uint)bpos[e]) >> 13], 1u);
            }
        }
        __syncthreads();

        // wave 0 scans; waves 8-15 issue the global cursor atomics concurrently.
        wave_scan512(hist, lbase, t);
        if (t >= 512) gbase[t - 512] = atomicAdd(&gcur[t - 512], hist[t - 512]);
        __syncthreads();

        // emit into LDS-staged counting sort (pure register/LDS, no value)
        auto emit = [&](int p, int tk, int pi) {
            uint b = ((uint)p) >> 13;
            u64 rec = (u64)(uint)(p & (PPB - 1))
                    | ((u64)(uint)tk << 13)
                    | ((u64)(uint)pi << 34)
                    | ((u64)b << 55);
            uint off = lbase[b] + atomicAdd(&lcur[b], 1u);
            stage[off] = rec;
        };
        if (vec) {
            emit(b0.x, k0.x, p0.x); emit(b0.y, k0.y, p0.y);
            emit(b0.z, k0.z, p0.z); emit(b0.w, k0.w, p0.w);
            emit(b1.x, k1.x, p1.x); emit(b1.y, k1.y, p1.y);
            emit(b1.z, k1.z, p1.z); emit(b1.w, k1.w, p1.w);
        } else {
            for (int j = 0; j < A_EPT; ++j) {
                int e = be + j;
                if (e < E) emit(bpos[e], tidx[e], pidx[e]);
            }
        }

        // prefetch next chunk's streams NOW (registers are dead after emit);
        // the ~900cy HBM latency drains under the barrier + writeout below.
        bool nvec = false;
        if (cc + 1 < A_CPB) {
            int nbe = (c + 1) * A_CHUNK + t * A_EPT;
            nvec = (nbe + A_EPT) <= E;
            if (nvec) {
                b0 = __builtin_nontemporal_load((const vi4*)(bpos + nbe));
                b1 = __builtin_nontemporal_load((const vi4*)(bpos + nbe + 4));
                p0 = __builtin_nontemporal_load((const vi4*)(pidx + nbe));
                p1 = __builtin_nontemporal_load((const vi4*)(pidx + nbe + 4));
                k0 = __builtin_nontemporal_load((const vi4*)(tidx + nbe));
                k1 = __builtin_nontemporal_load((const vi4*)(tidx + nbe + 4));
            }
        }
        __syncthreads();

        // write-out: bucket id from record bits; NORMAL cached stores
        // -> L2 write-combines runs, records stay L3-resident for phaseC.
        uint total = lbase[NB];
        for (uint i = t; i < total; i += A_THREADS) {
            u64 rc = stage[i];
            int b = (int)(rc >> 55);
            uint dst = gbase[b] + (i - lbase[b]);
            if (dst < (uint)CAP)
                recs[(size_t)b * CAP + dst] = rc;
        }
        vec = nvec;
    }
}

// ------- Phase C: per byte-bucket accumulate + emit token-bucket recs -------
constexpr int C_THREADS = 1024;
constexpr int C_CHUNK   = 8192;
constexpr int C_MAXCH   = (CAP + C_CHUNK - 1) / C_CHUNK;   // 3

__global__ __launch_bounds__(C_THREADS, 8) void phaseC(
    const float* __restrict__ fp,
    const u64* __restrict__ recs, const uint* __restrict__ gcur,
    uint* __restrict__ rec2, uint* __restrict__ gcur2)
{
    __shared__ uint acc[PPB];               // 32 KB
    __shared__ uint stage2[C_CHUNK];        // 32 KB
    __shared__ uint histc[C_MAXCH][NB2];    // 3 KB
    __shared__ uint lcur[NB2], gb[NB2], lbase[NB2 + 1];   // ~3 KB
    int t = threadIdx.x;
    int b = blockIdx.x;
    for (int i = t; i < PPB; i += C_THREADS) acc[i] = 0u;
    for (int i = t; i < C_MAXCH * NB2; i += C_THREADS) (&histc[0][0])[i] = 0u;
    if (t < NB2) lcur[t] = 0u;
    __syncthreads();

    uint n = min(gcur[b], (uint)CAP);
    const u64* r = recs + (size_t)b * CAP;

    // pass 1: strip-mined x4 with COALESCED stride (each NT load = 1KB/wave).
    // 4 independent rec loads -> 8 independent fp gathers -> 16 LDS atomics.
    auto upd = [&](u64 rc, float v, uint ch) {
        int fx = (int)rintf(v * V_SCALE);
        atomicAdd(&acc[(uint)rc & (PPB - 1)], (uint)((1 << 26) + fx));
        atomicAdd(&histc[ch][(uint)(rc >> 26) & 0xFFu], 1u);  // tok>>13
    };
    uint np = n >> 1;                        // uv2 pairs
    const uv2* pr = (const uv2*)r;
    uint i = t;
    for (; i + 3u * C_THREADS < np; i += 4u * C_THREADS) {
        uv2 x0 = __builtin_nontemporal_load(pr + i);
        uv2 x1 = __builtin_nontemporal_load(pr + i + C_THREADS);
        uv2 x2 = __builtin_nontemporal_load(pr + i + 2u * C_THREADS);
        uv2 x3 = __builtin_nontemporal_load(pr + i + 3u * C_THREADS);
        float v0 = fp[(uint)(x0.x >> 34) & 0x1FFFFFu];
        float v1 = fp[(uint)(x0.y >> 34) & 0x1FFFFFu];
        float v2 = fp[(uint)(x1.x >> 34) & 0x1FFFFFu];
        float v3 = fp[(uint)(x1.y >> 34) & 0x1FFFFFu];
        float v4 = fp[(uint)(x2.x >> 34) & 0x1FFFFFu];
        float v5 = fp[(uint)(x2.y >> 34) & 0x1FFFFFu];
        float v6 = fp[(uint)(x3.x >> 34) & 0x1FFFFFu];
        float v7 = fp[(uint)(x3.y >> 34) & 0x1FFFFFu];
        uint c0 = i >> 12;                         // pair>>12 == elem>>13
        uint c1 = (i + C_THREADS) >> 12;
        uint c2 = (i + 2u * C_THREADS) >> 12;
        uint c3 = (i + 3u * C_THREADS) >> 12;
        upd(x0.x, v0, c0); upd(x0.y, v1, c0);
        upd(x1.x, v2, c1); upd(x1.y, v3, c1);
        upd(x2.x, v4, c2); upd(x2.y, v5, c2);
        upd(x3.x, v6, c3); upd(x3.y, v7, c3);
    }
    for (; i < np; i += C_THREADS) {
        uv2 x = __builtin_nontemporal_load(pr + i);
        uint ch = i >> 12;
        float va = fp[(uint)(x.x >> 34) & 0x1FFFFFu];
        float vb = fp[(uint)(x.y >> 34) & 0x1FFFFFu];
        upd(x.x, va, ch); upd(x.y, vb, ch);
    }
    if ((n & 1u) && t == 0) {
        u64 rc = __builtin_nontemporal_load(r + n - 1);
        upd(rc, fp[(uint)(rc >> 34) & 0x1FFFFFu], (n - 1) / C_CHUNK);
    }
    __syncthreads();

    // ONE global-cursor atomic per bucket per block (wave 8), overlapped
    // with wave 0's chunk-0 scan below.
    if (t >= 512 && t < 512 + NB2) {
        int tb = t - 512;
        uint tot = histc[0][tb];
        #pragma unroll
        for (int c = 1; c < C_MAXCH; ++c) tot += histc[c][tb];
        gb[tb] = atomicAdd(&gcur2[tb], tot);
    }

    // pass 2: strip-mined x2 chunked decode + LDS-staged emit + write-out.
    // gb/lcur update folded into write-out (bucket tb owned by wave tb%16
    // in EVERY chunk -> no cross-wave hazard) -> 3 barriers/chunk, not 4.
    auto emit = [&](u64 rc, uint a) {
        uint tok = (uint)(rc >> 13) & 0x1FFFFFu;
        uint c = (a + (1u << 25)) >> 26;        // exact count >= 1
        int s = (int)(a - (c << 26));           // signed sum * 2^21
        float w = (float)s * V_INV / (float)c;
        int wfx = (int)rintf(w * W_SCALE);
        uint tb = tok >> 13;
        uint off = lbase[tb] + atomicAdd(&lcur[tb], 1u);
        stage2[off] = (tok & (TOKB - 1)) | ((uint)wfx << 13);
    };
    uint ch = 0;
    for (uint c0 = 0; c0 < n; c0 += C_CHUNK, ++ch) {
        uint m = min((uint)C_CHUNK, n - c0);
        wave_scan256(histc[ch], lbase, t);
        __syncthreads();

        uint mp = m >> 1;
        const uv2* pc = (const uv2*)(r + c0);
        uint j = t;
        for (; j + C_THREADS < mp; j += 2u * C_THREADS) {
            uv2 x0 = __builtin_nontemporal_load(pc + j);
            uv2 x1 = __builtin_nontemporal_load(pc + j + C_THREADS);
            uint a0 = acc[(uint)x0.x & (PPB - 1)];
            uint a1 = acc[(uint)x0.y & (PPB - 1)];
            uint a2 = acc[(uint)x1.x & (PPB - 1)];
            uint a3 = acc[(uint)x1.y & (PPB - 1)];
            emit(x0.x, a0); emit(x0.y, a1);
            emit(x1.x, a2); emit(x1.y, a3);
        }
        for (; j < mp; j += C_THREADS) {
            uv2 x = __builtin_nontemporal_load(pc + j);
            uint a0 = acc[(uint)x.x & (PPB - 1)];
            uint a1 = acc[(uint)x.y & (PPB - 1)];
            emit(x.x, a0); emit(x.y, a1);
        }
        if ((m & 1u) && t == 0) {
            u64 rc = __builtin_nontemporal_load(r + c0 + m - 1);
            emit(rc, acc[(uint)rc & (PPB - 1)]);
        }
        __syncthreads();
        // write-out: wave w copies buckets w, w+16, ... as contiguous runs
        // (normal cached stores -> rec2 stays L3-resident for phaseD).
        // lane 0 of the owning wave advances gb and resets lcur in-place.
        int w = t >> 6, lane = t & 63;
        for (int tb = w; tb < NB2; tb += 16) {
            uint base = lbase[tb];
            uint len  = lbase[tb + 1] - base;
            uint g    = gb[tb];
            for (uint q = lane; q < len; q += 64) {
                uint dst = g + q;
                if (dst < (uint)CAP2)
                    rec2[(size_t)tb * CAP2 + dst] = stage2[base + q];
            }
            if (lane == 0) { gb[tb] = g + len; lcur[tb] = 0u; }
        }
        __syncthreads();
    }
}

// ---------------- Phase D: per token-bucket reduce + output ----------------
constexpr int D_THREADS = 1024;

__global__ __launch_bounds__(D_THREADS) void phaseD(
    const uint* __restrict__ rec2, const uint* __restrict__ gcur2,
    float* __restrict__ out, int N)
{
    __shared__ int facc[TOKB];   // 32 KB
    int t = threadIdx.x;
    int b = blockIdx.x;
    for (int i = t; i < TOKB; i += D_THREADS) facc[i] = 0;
    __syncthreads();
    uint n = min(gcur2[b], (uint)CAP2);
    const uint* r = rec2 + (size_t)b * CAP2;
    uint n4 = n >> 2;
    uint i = t;
    // 4-deep coalesced load batching: 4 independent uint4 loads, then 16
    // fire-and-forget LDS atomics (probe: does phaseD respond to MLP?)
    for (; i + 3u * D_THREADS < n4; i += 4u * D_THREADS) {
        uint4 q0 = ((const uint4*)r)[i];
        uint4 q1 = ((const uint4*)r)[i + D_THREADS];
        uint4 q2 = ((const uint4*)r)[i + 2u * D_THREADS];
        uint4 q3 = ((const uint4*)r)[i + 3u * D_THREADS];
        atomicAdd(&facc[q0.x & (TOKB - 1)], ((int)q0.x) >> 13);
        atomicAdd(&facc[q0.y & (TOKB - 1)], ((int)q0.y) >> 13);
        atomicAdd(&facc[q0.z & (TOKB - 1)], ((int)q0.z) >> 13);
        atomicAdd(&facc[q0.w & (TOKB - 1)], ((int)q0.w) >> 13);
        atomicAdd(&facc[q1.x & (TOKB - 1)], ((int)q1.x) >> 13);
        atomicAdd(&facc[q1.y & (TOKB - 1)], ((int)q1.y) >> 13);
        atomicAdd(&facc[q1.z & (TOKB - 1)], ((int)q1.z) >> 13);
        atomicAdd(&facc[q1.w & (TOKB - 1)], ((int)q1.w) >> 13);
        atomicAdd(&facc[q2.x & (TOKB - 1)], ((int)q2.x) >> 13);
        atomicAdd(&facc[q2.y & (TOKB - 1)], ((int)q2.y) >> 13);
        atomicAdd(&facc[q2.z & (TOKB - 1)], ((int)q2.z) >> 13);
        atomicAdd(&facc[q2.w & (TOKB - 1)], ((int)q2.w) >> 13);
        atomicAdd(&facc[q3.x & (TOKB - 1)], ((int)q3.x) >> 13);
        atomicAdd(&facc[q3.y & (TOKB - 1)], ((int)q3.y) >> 13);
        atomicAdd(&facc[q3.z & (TOKB - 1)], ((int)q3.z) >> 13);
        atomicAdd(&facc[q3.w & (TOKB - 1)], ((int)q3.w) >> 13);
    }
    for (; i < n4; i += D_THREADS) {
        uint4 q = ((const uint4*)r)[i];
        atomicAdd(&facc[q.x & (TOKB - 1)], ((int)q.x) >> 13);
        atomicAdd(&facc[q.y & (TOKB - 1)], ((int)q.y) >> 13);
        atomicAdd(&facc[q.z & (TOKB - 1)], ((int)q.z) >> 13);
        atomicAdd(&facc[q.w & (TOKB - 1)], ((int)q.w) >> 13);
    }
    for (uint k = (n4 << 2) + t; k < n; k += D_THREADS) {
        uint rc = r[k];
        atomicAdd(&facc[rc & (TOKB - 1)], ((int)rc) >> 13);
    }
    __syncthreads();
    int base = b * TOKB;
    for (int i2 = t; i2 < TOKB; i2 += D_THREADS) {
        int idx = base + i2;
        if (idx < N)
            __builtin_nontemporal_store((float)facc[i2] * W_INV, &out[idx]);
    }
}

// ---------------- fallback (R2 path) if workspace too small ----------------
__global__ void fb_scatter(const float* __restrict__ fp,
                           const int* __restrict__ pidx,
                           const int* __restrict__ bpos,
                           u64* __restrict__ bacc, int E) {
    int e = blockIdx.x * blockDim.x + threadIdx.x;
    if (e < E) {
        float v = fp[pidx[e]];
        long long fx = (long long)rintf(v * 4294967296.0f);
        atomicAdd(&bacc[bpos[e]], (1ULL << 39) + (u64)fx);
    }
}

__global__ void fb_tokens(const u64* __restrict__ bacc,
                          const int* __restrict__ bpos,
                          const int* __restrict__ tidx,
                          float* __restrict__ out, int E) {
    int e = blockIdx.x * blockDim.x + threadIdx.x;
    if (e < E) {
        u64 v = bacc[bpos[e]];
        long long cnt = (long long)((v + (1ULL << 38)) >> 39);
        long long s   = (long long)(v - ((u64)cnt << 39));
        atomicAdd(&out[tidx[e]], (float)s * (1.0f / 4294967296.0f) / (float)cnt);
    }
}

extern "C" void kernel_launch(void* const* d_in, const int* in_sizes, int n_in,
                              void* d_out, int out_size, void* d_ws, size_t ws_size,
                              hipStream_t stream) {
    const float* flat_params   = (const float*)d_in[0];
    const int*   occ_param_idx = (const int*)d_in[1];
    const int*   occ_byte_pos  = (const int*)d_in[2];
    const int*   occ_token_idx = (const int*)d_in[3];

    const int P = in_sizes[0];            // 1,048,576
    const int E = in_sizes[1];            // 8,388,608
    const int N = out_size;               // 2,097,152

    const size_t REC_BYTES  = (size_t)NB  * CAP  * 8;   // 71.3 MB
    const size_t REC2_BYTES = (size_t)NB2 * CAP2 * 4;   // 35.7 MB
    const size_t NEED = 4096 + REC_BYTES + REC2_BYTES;  // ~107 MB

    if (ws_size >= NEED && N <= NB2 * TOKB && P <= (1 << 21)) {
        uint* gcur  = (uint*)d_ws;                  // 2 KB (512 u32)
        uint* gcur2 = (uint*)((char*)d_ws + 2048);  // 1 KB (256 u32)
        u64* recs = (u64*)((char*)d_ws + 4096);
        uint* rec2 = (uint*)((char*)d_ws + 4096 + REC_BYTES);

        (void)hipMemsetAsync(d_ws, 0, 4096, stream);   // both cursor arrays

        int nchunks = (E + A_CHUNK - 1) / A_CHUNK;          // 1024
        int gridA = (nchunks + A_CPB - 1) / A_CPB;          // 512
        phaseA<<<gridA, A_THREADS, 0, stream>>>(occ_param_idx, occ_byte_pos,
                                                occ_token_idx, recs, gcur, E);
        phaseC<<<NB, C_THREADS, 0, stream>>>(flat_params, recs, gcur,
                                             rec2, gcur2);
        phaseD<<<NB2, D_THREADS, 0, stream>>>(rec2, gcur2, (float*)d_out, N);
    } else {
        u64* bacc = (u64*)d_ws;
        (void)hipMemsetAsync(bacc, 0, (size_t)4194304 * 8, stream);
        (void)hipMemsetAsync(d_out, 0, (size_t)N * sizeof(float), stream);
        int gridE = (E + 255) / 256;
        fb_scatter<<<gridE, 256, 0, stream>>>(flat_params, occ_param_idx,
                                              occ_byte_pos, bacc, E);
        fb_tokens<<<gridE, 256, 0, stream>>>(bacc, occ_byte_pos,
                                             occ_token_idx, (float*)d_out, E);
    }
}

// Round 6
// 242.788 us; speedup vs baseline: 1.0865x; 1.0061x over previous
//
#include <hip/hip_runtime.h>

// P=1,048,576 params; E=8,388,608 edges; T=4,194,304 bytes; N=2,097,152 tokens.
//
// Measured HW facts driving this design:
//  - global atomicAdd caps at ~20.4 G/s regardless of locality (R1-R3) -> no
//    global atomics in hot paths; all accumulation in LDS.
//  - isolated small scattered stores cause ~3x write RMW amplification (R4) ->
//    scattered global writes staged via in-LDS counting sort, written as runs
//    of >=128B (R15: 64B runs re-trigger RMW: WRITE +6.5MB, FETCH +10MB).
//  - NT loads on read-once input streams keep the fp table L2-resident (R10).
//  - R11 cache-policy split: intermediates (recs, rec2) written with normal
//    cached stores so L2 write-combines and they stay L3-resident.
//  - R12: records carry pidx instead of fx -> phaseA gather-free; gather in
//    phaseC pass 1. phaseA 93 -> ~81us; phaseC 89us (latency-bound, VGPR=20).
//  - R13 REGRESSION (reverted): per-thread-contiguous NT batching broke
//    coalescing. Lesson: MLP batching must keep wave-coalesced stride.
//  - R15: strip-mined MLP (coalesced) works: VALUBusy 21->28.6. NB2=512
//    reverted (64B runs -> RMW). phaseD 2blk/CU: NO effect.
//  - R16: NB2=256 + strip-mine + barrier fold: phaseC 91->82.7, total 244.3
//    (best). Residual reconstruction: A ~= 81, D ~= 80 (both below top-5
//    cutoff 81.4, sum 162). A+D invariant ~160-163 across R15/R16 despite
//    D restructures. phaseD at 0.53 TB/s with ~5us of modelable work is a
//    10x model gap - UNDIAGNOSED, counters never seen.
//  - R17 (this round): mirror the x4 strip-mine in phaseC pass 2 to push C
//    below A and D -> next round's top-5 surfaces phaseA AND phaseD counters
//    (diagnosis round). A and D byte-identical to R16 as controls.
//
// rec64 = pos_low(13) | tok(21)<<13 | pidx(21)<<34 | bucket(9)<<55.
// acc u32 = cnt*2^26 + sum(fx), fx = round(fp[pidx] * 2^21)  (cnt<=~25).
// rec2 = tok_low(13) | wfx<<13,  wfx = round(w * 2^19) (19-bit signed).

typedef unsigned long long u64;
typedef unsigned int uint;
typedef int  vi4  __attribute__((ext_vector_type(4)));
typedef unsigned long long uv2 __attribute__((ext_vector_type(2)));

constexpr int NB   = 512;        // byte buckets  (bpos >> 13)
constexpr int PPB  = 8192;       // positions per byte bucket
constexpr int NB2  = 256;        // token buckets (tok >> 13)
constexpr int TOKB = 8192;       // tokens per token bucket
constexpr int CAP  = 17408;      // per-bucket capacity (mean 16384 + 8 sigma)
constexpr int CAP2 = 34816;      // per-token-bucket capacity (mean 32768 + 11s)

constexpr float V_SCALE = 2097152.0f;        // 2^21
constexpr float V_INV   = 1.0f / 2097152.0f;
constexpr float W_SCALE = 524288.0f;         // 2^19
constexpr float W_INV   = 1.0f / 524288.0f;

// Exclusive scan of 512 LDS entries by wave 0 only. lbase[512] = total.
__device__ __forceinline__ void wave_scan512(const uint* hist, uint* lbase,
                                             int t) {
    if (t < 64) {
        uint h[8];
        uint run = 0;
        #pragma unroll
        for (int j = 0; j < 8; ++j) { h[j] = run; run += hist[t * 8 + j]; }
        uint tot = run, inc = tot;
        #pragma unroll
        for (int d = 1; d < 64; d <<= 1) {
            uint up = __shfl_up(inc, d, 64);
            if (t >= d) inc += up;
        }
        uint excl = inc - tot;
        #pragma unroll
        for (int j = 0; j < 8; ++j) lbase[t * 8 + j] = excl + h[j];
        if (t == 63) lbase[512] = inc;
    }
}

// Exclusive scan of 256 LDS entries by wave 0 only. lbase[256] = total.
__device__ __forceinline__ void wave_scan256(const uint* hist, uint* lbase,
                                             int t) {
    if (t < 64) {
        uint h[4];
        uint run = 0;
        #pragma unroll
        for (int j = 0; j < 4; ++j) { h[j] = run; run += hist[t * 4 + j]; }
        uint tot = run, inc = tot;
        #pragma unroll
        for (int d = 1; d < 64; d <<= 1) {
            uint up = __shfl_up(inc, d, 64);
            if (t >= d) inc += up;
        }
        uint excl = inc - tot;
        #pragma unroll
        for (int j = 0; j < 4; ++j) lbase[t * 4 + j] = excl + h[j];
        if (t == 63) lbase[256] = inc;
    }
}

// ---------------- Phase A: bin edges into 512 byte-buckets ----------------
// Gather-free streaming sort; persistent blocks, 2 chunks each, prefetched.
constexpr int A_THREADS = 1024;
constexpr int A_EPT     = 8;
constexpr int A_CHUNK   = A_THREADS * A_EPT;   // 8192
constexpr int A_CPB     = 2;                   // chunks per block

__global__ __launch_bounds__(A_THREADS, 8) void phaseA(
    const int* __restrict__ pidx, const int* __restrict__ bpos,
    const int* __restrict__ tidx, u64* __restrict__ recs,
    uint* __restrict__ gcur, int E)
{
    __shared__ u64 stage[A_CHUNK];                 // 64 KB
    __shared__ uint hist[NB], lcur[NB], gbase[NB], lbase[NB + 1];  // ~8 KB
    int t = threadIdx.x;

    int c = blockIdx.x * A_CPB;
    int be0 = c * A_CHUNK + t * A_EPT;
    bool vec = (be0 + A_EPT) <= E;

    // initial NT loads of all three read-once streams for chunk 0
    vi4 b0, b1, p0, p1, k0, k1;
    if (vec) {
        b0 = __builtin_nontemporal_load((const vi4*)(bpos + be0));
        b1 = __builtin_nontemporal_load((const vi4*)(bpos + be0 + 4));
        p0 = __builtin_nontemporal_load((const vi4*)(pidx + be0));
        p1 = __builtin_nontemporal_load((const vi4*)(pidx + be0 + 4));
        k0 = __builtin_nontemporal_load((const vi4*)(tidx + be0));
        k1 = __builtin_nontemporal_load((const vi4*)(tidx + be0 + 4));
    }

    for (int cc = 0; cc < A_CPB; ++cc, ++c) {
        if (t < NB) { hist[t] = 0u; lcur[t] = 0u; }
        __syncthreads();

        int be = c * A_CHUNK + t * A_EPT;
        if (vec) {
            atomicAdd(&hist[((uint)b0.x) >> 13], 1u);
            atomicAdd(&hist[((uint)b0.y) >> 13], 1u);
            atomicAdd(&hist[((uint)b0.z) >> 13], 1u);
            atomicAdd(&hist[((uint)b0.w) >> 13], 1u);
            atomicAdd(&hist[((uint)b1.x) >> 13], 1u);
            atomicAdd(&hist[((uint)b1.y) >> 13], 1u);
            atomicAdd(&hist[((uint)b1.z) >> 13], 1u);
            atomicAdd(&hist[((uint)b1.w) >> 13], 1u);
        } else {
            for (int j = 0; j < A_EPT; ++j) {
                int e = be + j;
                if (e < E) atomicAdd(&hist[((uint)bpos[e]) >> 13], 1u);
            }
        }
        __syncthreads();

        // wave 0 scans; waves 8-15 issue the global cursor atomics concurrently.
        wave_scan512(hist, lbase, t);
        if (t >= 512) gbase[t - 512] = atomicAdd(&gcur[t - 512], hist[t - 512]);
        __syncthreads();

        // emit into LDS-staged counting sort (pure register/LDS, no value)
        auto emit = [&](int p, int tk, int pi) {
            uint b = ((uint)p) >> 13;
            u64 rec = (u64)(uint)(p & (PPB - 1))
                    | ((u64)(uint)tk << 13)
                    | ((u64)(uint)pi << 34)
                    | ((u64)b << 55);
            uint off = lbase[b] + atomicAdd(&lcur[b], 1u);
            stage[off] = rec;
        };
        if (vec) {
            emit(b0.x, k0.x, p0.x); emit(b0.y, k0.y, p0.y);
            emit(b0.z, k0.z, p0.z); emit(b0.w, k0.w, p0.w);
            emit(b1.x, k1.x, p1.x); emit(b1.y, k1.y, p1.y);
            emit(b1.z, k1.z, p1.z); emit(b1.w, k1.w, p1.w);
        } else {
            for (int j = 0; j < A_EPT; ++j) {
                int e = be + j;
                if (e < E) emit(bpos[e], tidx[e], pidx[e]);
            }
        }

        // prefetch next chunk's streams NOW (registers are dead after emit);
        // the ~900cy HBM latency drains under the barrier + writeout below.
        bool nvec = false;
        if (cc + 1 < A_CPB) {
            int nbe = (c + 1) * A_CHUNK + t * A_EPT;
            nvec = (nbe + A_EPT) <= E;
            if (nvec) {
                b0 = __builtin_nontemporal_load((const vi4*)(bpos + nbe));
                b1 = __builtin_nontemporal_load((const vi4*)(bpos + nbe + 4));
                p0 = __builtin_nontemporal_load((const vi4*)(pidx + nbe));
                p1 = __builtin_nontemporal_load((const vi4*)(pidx + nbe + 4));
                k0 = __builtin_nontemporal_load((const vi4*)(tidx + nbe));
                k1 = __builtin_nontemporal_load((const vi4*)(tidx + nbe + 4));
            }
        }
        __syncthreads();

        // write-out: bucket id from record bits; NORMAL cached stores
        // -> L2 write-combines runs, records stay L3-resident for phaseC.
        uint total = lbase[NB];
        for (uint i = t; i < total; i += A_THREADS) {
            u64 rc = stage[i];
            int b = (int)(rc >> 55);
            uint dst = gbase[b] + (i - lbase[b]);
            if (dst < (uint)CAP)
                recs[(size_t)b * CAP + dst] = rc;
        }
        vec = nvec;
    }
}

// ------- Phase C: per byte-bucket accumulate + emit token-bucket recs -------
constexpr int C_THREADS = 1024;
constexpr int C_CHUNK   = 8192;
constexpr int C_MAXCH   = (CAP + C_CHUNK - 1) / C_CHUNK;   // 3

__global__ __launch_bounds__(C_THREADS, 8) void phaseC(
    const float* __restrict__ fp,
    const u64* __restrict__ recs, const uint* __restrict__ gcur,
    uint* __restrict__ rec2, uint* __restrict__ gcur2)
{
    __shared__ uint acc[PPB];               // 32 KB
    __shared__ uint stage2[C_CHUNK];        // 32 KB
    __shared__ uint histc[C_MAXCH][NB2];    // 3 KB
    __shared__ uint lcur[NB2], gb[NB2], lbase[NB2 + 1];   // ~3 KB
    int t = threadIdx.x;
    int b = blockIdx.x;
    for (int i = t; i < PPB; i += C_THREADS) acc[i] = 0u;
    for (int i = t; i < C_MAXCH * NB2; i += C_THREADS) (&histc[0][0])[i] = 0u;
    if (t < NB2) lcur[t] = 0u;
    __syncthreads();

    uint n = min(gcur[b], (uint)CAP);
    const u64* r = recs + (size_t)b * CAP;

    // pass 1: strip-mined x4 with COALESCED stride (each NT load = 1KB/wave).
    // 4 independent rec loads -> 8 independent fp gathers -> 16 LDS atomics.
    auto upd = [&](u64 rc, float v, uint ch) {
        int fx = (int)rintf(v * V_SCALE);
        atomicAdd(&acc[(uint)rc & (PPB - 1)], (uint)((1 << 26) + fx));
        atomicAdd(&histc[ch][(uint)(rc >> 26) & 0xFFu], 1u);  // tok>>13
    };
    uint np = n >> 1;                        // uv2 pairs
    const uv2* pr = (const uv2*)r;
    uint i = t;
    for (; i + 3u * C_THREADS < np; i += 4u * C_THREADS) {
        uv2 x0 = __builtin_nontemporal_load(pr + i);
        uv2 x1 = __builtin_nontemporal_load(pr + i + C_THREADS);
        uv2 x2 = __builtin_nontemporal_load(pr + i + 2u * C_THREADS);
        uv2 x3 = __builtin_nontemporal_load(pr + i + 3u * C_THREADS);
        float v0 = fp[(uint)(x0.x >> 34) & 0x1FFFFFu];
        float v1 = fp[(uint)(x0.y >> 34) & 0x1FFFFFu];
        float v2 = fp[(uint)(x1.x >> 34) & 0x1FFFFFu];
        float v3 = fp[(uint)(x1.y >> 34) & 0x1FFFFFu];
        float v4 = fp[(uint)(x2.x >> 34) & 0x1FFFFFu];
        float v5 = fp[(uint)(x2.y >> 34) & 0x1FFFFFu];
        float v6 = fp[(uint)(x3.x >> 34) & 0x1FFFFFu];
        float v7 = fp[(uint)(x3.y >> 34) & 0x1FFFFFu];
        uint c0 = i >> 12;                         // pair>>12 == elem>>13
        uint c1 = (i + C_THREADS) >> 12;
        uint c2 = (i + 2u * C_THREADS) >> 12;
        uint c3 = (i + 3u * C_THREADS) >> 12;
        upd(x0.x, v0, c0); upd(x0.y, v1, c0);
        upd(x1.x, v2, c1); upd(x1.y, v3, c1);
        upd(x2.x, v4, c2); upd(x2.y, v5, c2);
        upd(x3.x, v6, c3); upd(x3.y, v7, c3);
    }
    for (; i < np; i += C_THREADS) {
        uv2 x = __builtin_nontemporal_load(pr + i);
        uint ch = i >> 12;
        float va = fp[(uint)(x.x >> 34) & 0x1FFFFFu];
        float vb = fp[(uint)(x.y >> 34) & 0x1FFFFFu];
        upd(x.x, va, ch); upd(x.y, vb, ch);
    }
    if ((n & 1u) && t == 0) {
        u64 rc = __builtin_nontemporal_load(r + n - 1);
        upd(rc, fp[(uint)(rc >> 34) & 0x1FFFFFu], (n - 1) / C_CHUNK);
    }
    __syncthreads();

    // ONE global-cursor atomic per bucket per block (wave 8), overlapped
    // with wave 0's chunk-0 scan below.
    if (t >= 512 && t < 512 + NB2) {
        int tb = t - 512;
        uint tot = histc[0][tb];
        #pragma unroll
        for (int c = 1; c < C_MAXCH; ++c) tot += histc[c][tb];
        gb[tb] = atomicAdd(&gcur2[tb], tot);
    }

    // pass 2: strip-mined x4 chunked decode + LDS-staged emit + write-out.
    // 4 independent NT rec loads -> 8 independent acc[] LDS reads -> 8 emits.
    // gb/lcur update folded into write-out (bucket tb owned by wave tb%16
    // in EVERY chunk -> no cross-wave hazard) -> 3 barriers/chunk, not 4.
    auto emit = [&](u64 rc, uint a) {
        uint tok = (uint)(rc >> 13) & 0x1FFFFFu;
        uint c = (a + (1u << 25)) >> 26;        // exact count >= 1
        int s = (int)(a - (c << 26));           // signed sum * 2^21
        float w = (float)s * V_INV / (float)c;
        int wfx = (int)rintf(w * W_SCALE);
        uint tb = tok >> 13;
        uint off = lbase[tb] + atomicAdd(&lcur[tb], 1u);
        stage2[off] = (tok & (TOKB - 1)) | ((uint)wfx << 13);
    };
    uint ch = 0;
    for (uint c0 = 0; c0 < n; c0 += C_CHUNK, ++ch) {
        uint m = min((uint)C_CHUNK, n - c0);
        wave_scan256(histc[ch], lbase, t);
        __syncthreads();

        uint mp = m >> 1;
        const uv2* pc = (const uv2*)(r + c0);
        uint j = t;
        for (; j + 3u * C_THREADS < mp; j += 4u * C_THREADS) {
            uv2 x0 = __builtin_nontemporal_load(pc + j);
            uv2 x1 = __builtin_nontemporal_load(pc + j + C_THREADS);
            uv2 x2 = __builtin_nontemporal_load(pc + j + 2u * C_THREADS);
            uv2 x3 = __builtin_nontemporal_load(pc + j + 3u * C_THREADS);
            uint a0 = acc[(uint)x0.x & (PPB - 1)];
            uint a1 = acc[(uint)x0.y & (PPB - 1)];
            uint a2 = acc[(uint)x1.x & (PPB - 1)];
            uint a3 = acc[(uint)x1.y & (PPB - 1)];
            uint a4 = acc[(uint)x2.x & (PPB - 1)];
            uint a5 = acc[(uint)x2.y & (PPB - 1)];
            uint a6 = acc[(uint)x3.x & (PPB - 1)];
            uint a7 = acc[(uint)x3.y & (PPB - 1)];
            emit(x0.x, a0); emit(x0.y, a1);
            emit(x1.x, a2); emit(x1.y, a3);
            emit(x2.x, a4); emit(x2.y, a5);
            emit(x3.x, a6); emit(x3.y, a7);
        }
        for (; j < mp; j += C_THREADS) {
            uv2 x = __builtin_nontemporal_load(pc + j);
            uint a0 = acc[(uint)x.x & (PPB - 1)];
            uint a1 = acc[(uint)x.y & (PPB - 1)];
            emit(x.x, a0); emit(x.y, a1);
        }
        if ((m & 1u) && t == 0) {
            u64 rc = __builtin_nontemporal_load(r + c0 + m - 1);
            emit(rc, acc[(uint)rc & (PPB - 1)]);
        }
        __syncthreads();
        // write-out: wave w copies buckets w, w+16, ... as contiguous runs
        // (normal cached stores -> rec2 stays L3-resident for phaseD).
        // lane 0 of the owning wave advances gb and resets lcur in-place.
        int w = t >> 6, lane = t & 63;
        for (int tb = w; tb < NB2; tb += 16) {
            uint base = lbase[tb];
            uint len  = lbase[tb + 1] - base;
            uint g    = gb[tb];
            for (uint q = lane; q < len; q += 64) {
                uint dst = g + q;
                if (dst < (uint)CAP2)
                    rec2[(size_t)tb * CAP2 + dst] = stage2[base + q];
            }
            if (lane == 0) { gb[tb] = g + len; lcur[tb] = 0u; }
        }
        __syncthreads();
    }
}

// ---------------- Phase D: per token-bucket reduce + output ----------------
constexpr int D_THREADS = 1024;

__global__ __launch_bounds__(D_THREADS) void phaseD(
    const uint* __restrict__ rec2, const uint* __restrict__ gcur2,
    float* __restrict__ out, int N)
{
    __shared__ int facc[TOKB];   // 32 KB
    int t = threadIdx.x;
    int b = blockIdx.x;
    for (int i = t; i < TOKB; i += D_THREADS) facc[i] = 0;
    __syncthreads();
    uint n = min(gcur2[b], (uint)CAP2);
    const uint* r = rec2 + (size_t)b * CAP2;
    uint n4 = n >> 2;
    uint i = t;
    // 4-deep coalesced load batching: 4 independent uint4 loads, then 16
    // fire-and-forget LDS atomics (probe: does phaseD respond to MLP?)
    for (; i + 3u * D_THREADS < n4; i += 4u * D_THREADS) {
        uint4 q0 = ((const uint4*)r)[i];
        uint4 q1 = ((const uint4*)r)[i + D_THREADS];
        uint4 q2 = ((const uint4*)r)[i + 2u * D_THREADS];
        uint4 q3 = ((const uint4*)r)[i + 3u * D_THREADS];
        atomicAdd(&facc[q0.x & (TOKB - 1)], ((int)q0.x) >> 13);
        atomicAdd(&facc[q0.y & (TOKB - 1)], ((int)q0.y) >> 13);
        atomicAdd(&facc[q0.z & (TOKB - 1)], ((int)q0.z) >> 13);
        atomicAdd(&facc[q0.w & (TOKB - 1)], ((int)q0.w) >> 13);
        atomicAdd(&facc[q1.x & (TOKB - 1)], ((int)q1.x) >> 13);
        atomicAdd(&facc[q1.y & (TOKB - 1)], ((int)q1.y) >> 13);
        atomicAdd(&facc[q1.z & (TOKB - 1)], ((int)q1.z) >> 13);
        atomicAdd(&facc[q1.w & (TOKB - 1)], ((int)q1.w) >> 13);
        atomicAdd(&facc[q2.x & (TOKB - 1)], ((int)q2.x) >> 13);
        atomicAdd(&facc[q2.y & (TOKB - 1)], ((int)q2.y) >> 13);
        atomicAdd(&facc[q2.z & (TOKB - 1)], ((int)q2.z) >> 13);
        atomicAdd(&facc[q2.w & (TOKB - 1)], ((int)q2.w) >> 13);
        atomicAdd(&facc[q3.x & (TOKB - 1)], ((int)q3.x) >> 13);
        atomicAdd(&facc[q3.y & (TOKB - 1)], ((int)q3.y) >> 13);
        atomicAdd(&facc[q3.z & (TOKB - 1)], ((int)q3.z) >> 13);
        atomicAdd(&facc[q3.w & (TOKB - 1)], ((int)q3.w) >> 13);
    }
    for (; i < n4; i += D_THREADS) {
        uint4 q = ((const uint4*)r)[i];
        atomicAdd(&facc[q.x & (TOKB - 1)], ((int)q.x) >> 13);
        atomicAdd(&facc[q.y & (TOKB - 1)], ((int)q.y) >> 13);
        atomicAdd(&facc[q.z & (TOKB - 1)], ((int)q.z) >> 13);
        atomicAdd(&facc[q.w & (TOKB - 1)], ((int)q.w) >> 13);
    }
    for (uint k = (n4 << 2) + t; k < n; k += D_THREADS) {
        uint rc = r[k];
        atomicAdd(&facc[rc & (TOKB - 1)], ((int)rc) >> 13);
    }
    __syncthreads();
    int base = b * TOKB;
    for (int i2 = t; i2 < TOKB; i2 += D_THREADS) {
        int idx = base + i2;
        if (idx < N)
            __builtin_nontemporal_store((float)facc[i2] * W_INV, &out[idx]);
    }
}

// ---------------- fallback (R2 path) if workspace too small ----------------
__global__ void fb_scatter(const float* __restrict__ fp,
                           const int* __restrict__ pidx,
                           const int* __restrict__ bpos,
                           u64* __restrict__ bacc, int E) {
    int e = blockIdx.x * blockDim.x + threadIdx.x;
    if (e < E) {
        float v = fp[pidx[e]];
        long long fx = (long long)rintf(v * 4294967296.0f);
        atomicAdd(&bacc[bpos[e]], (1ULL << 39) + (u64)fx);
    }
}

__global__ void fb_tokens(const u64* __restrict__ bacc,
                          const int* __restrict__ bpos,
                          const int* __restrict__ tidx,
                          float* __restrict__ out, int E) {
    int e = blockIdx.x * blockDim.x + threadIdx.x;
    if (e < E) {
        u64 v = bacc[bpos[e]];
        long long cnt = (long long)((v + (1ULL << 38)) >> 39);
        long long s   = (long long)(v - ((u64)cnt << 39));
        atomicAdd(&out[tidx[e]], (float)s * (1.0f / 4294967296.0f) / (float)cnt);
    }
}

extern "C" void kernel_launch(void* const* d_in, const int* in_sizes, int n_in,
                              void* d_out, int out_size, void* d_ws, size_t ws_size,
                              hipStream_t stream) {
    const float* flat_params   = (const float*)d_in[0];
    const int*   occ_param_idx = (const int*)d_in[1];
    const int*   occ_byte_pos  = (const int*)d_in[2];
    const int*   occ_token_idx = (const int*)d_in[3];

    const int P = in_sizes[0];            // 1,048,576
    const int E = in_sizes[1];            // 8,388,608
    const int N = out_size;               // 2,097,152

    const size_t REC_BYTES  = (size_t)NB  * CAP  * 8;   // 71.3 MB
    const size_t REC2_BYTES = (size_t)NB2 * CAP2 * 4;   // 35.7 MB
    const size_t NEED = 4096 + REC_BYTES + REC2_BYTES;  // ~107 MB

    if (ws_size >= NEED && N <= NB2 * TOKB && P <= (1 << 21)) {
        uint* gcur  = (uint*)d_ws;                  // 2 KB (512 u32)
        uint* gcur2 = (uint*)((char*)d_ws + 2048);  // 1 KB (256 u32)
        u64* recs = (u64*)((char*)d_ws + 4096);
        uint* rec2 = (uint*)((char*)d_ws + 4096 + REC_BYTES);

        (void)hipMemsetAsync(d_ws, 0, 4096, stream);   // both cursor arrays

        int nchunks = (E + A_CHUNK - 1) / A_CHUNK;          // 1024
        int gridA = (nchunks + A_CPB - 1) / A_CPB;          // 512
        phaseA<<<gridA, A_THREADS, 0, stream>>>(occ_param_idx, occ_byte_pos,
                                                occ_token_idx, recs, gcur, E);
        phaseC<<<NB, C_THREADS, 0, stream>>>(flat_params, recs, gcur,
                                             rec2, gcur2);
        phaseD<<<NB2, D_THREADS, 0, stream>>>(rec2, gcur2, (float*)d_out, N);
    } else {
        u64* bacc = (u64*)d_ws;
        (void)hipMemsetAsync(bacc, 0, (size_t)4194304 * 8, stream);
        (void)hipMemsetAsync(d_out, 0, (size_t)N * sizeof(float), stream);
        int gridE = (E + 255) / 256;
        fb_scatter<<<gridE, 256, 0, stream>>>(flat_params, occ_param_idx,
                                              occ_byte_pos, bacc, E);
        fb_tokens<<<gridE, 256, 0, stream>>>(bacc, occ_byte_pos,
                                             occ_token_idx, (float*)d_out, E);
    }
}